// Round 1
// baseline (969.073 us; speedup 1.0000x reference)
//
#include <hip/hip_runtime.h>

#define BB 128
#define TT 1024
#define II 100
#define HH 200

// ---------------------------------------------------------------------------
// Phase 1: xp[r][j] = b_ih[j] + b_hh[j] + sum_i x[r][i] * W_ih[j][i]
// r = b*T + t (rows contiguous). Written into the hiddens region of d_out.
// One block = 256 threads handles 128 consecutive rows. W_ih row j lives in
// registers of thread j (100 VGPRs, static unroll); x rows staged in LDS and
// read as broadcast float4.
// ---------------------------------------------------------------------------
__global__ __launch_bounds__(256, 1) void rnn_xproj(
    const float* __restrict__ x, const float* __restrict__ Wih,
    const float* __restrict__ bih, const float* __restrict__ bhh,
    float* __restrict__ hid)
{
    __shared__ __align__(16) float xs[128 * II];  // 51.2 KB
    const int tid = threadIdx.x;
    const int j = tid;
    const int jl = (j < HH) ? j : (HH - 1);

    float w[II];
    const float4* wrow = (const float4*)(Wih + jl * II);
#pragma unroll
    for (int kk = 0; kk < II / 4; ++kk) {
        float4 v = wrow[kk];
        w[4 * kk + 0] = v.x; w[4 * kk + 1] = v.y;
        w[4 * kk + 2] = v.z; w[4 * kk + 3] = v.w;
    }
    const float bias = bih[jl] + bhh[jl];

    const long long r0 = (long long)blockIdx.x * 128;
    const float4* src = (const float4*)(x + r0 * II);
    float4* dst = (float4*)xs;
    for (int p = tid; p < 128 * II / 4; p += 256) dst[p] = src[p];
    __syncthreads();

    for (int row = 0; row < 128; ++row) {
        float acc0 = 0.f, acc1 = 0.f, acc2 = 0.f, acc3 = 0.f;
        const float4* xr = (const float4*)(xs + row * II);
#pragma unroll
        for (int kk = 0; kk < II / 4; ++kk) {
            float4 v = xr[kk];
            acc0 += w[4 * kk + 0] * v.x; acc1 += w[4 * kk + 1] * v.y;
            acc2 += w[4 * kk + 2] * v.z; acc3 += w[4 * kk + 3] * v.w;
        }
        if (j < HH)
            hid[(r0 + row) * HH + j] = bias + ((acc0 + acc1) + (acc2 + acc3));
    }
}

// ---------------------------------------------------------------------------
// Phase 2: the serial recurrence. One block per batch element (128 blocks),
// 256 threads. Thread j holds W_hh row j in registers (200 VGPRs, fully
// static after unroll). h double-buffered in LDS (broadcast reads).
// Reads xp from the hiddens region and overwrites the same row with h.
// ---------------------------------------------------------------------------
__global__ __launch_bounds__(256, 1) void rnn_recur(
    const float* __restrict__ Whh, float* __restrict__ hid)
{
    __shared__ __align__(16) float hbuf[2][HH + 8];
    const int tid = threadIdx.x;
    const int j = tid;
    const int jl = (j < HH) ? j : (HH - 1);

    float w[HH];
    const float4* wrow = (const float4*)(Whh + jl * HH);
#pragma unroll
    for (int kk = 0; kk < HH / 4; ++kk) {
        float4 v = wrow[kk];
        w[4 * kk + 0] = v.x; w[4 * kk + 1] = v.y;
        w[4 * kk + 2] = v.z; w[4 * kk + 3] = v.w;
    }

    if (tid < HH) { hbuf[0][tid] = 0.f; }
    __syncthreads();

    float* rowp = hid + (long long)blockIdx.x * TT * HH;
    int cur = 0;
    for (int t = 0; t < TT; ++t) {
        float xpv = (j < HH) ? rowp[j] : 0.f;  // issued before the FMA loop
        float acc0 = 0.f, acc1 = 0.f, acc2 = 0.f, acc3 = 0.f;
        const float4* hr = (const float4*)hbuf[cur];
#pragma unroll
        for (int kk = 0; kk < HH / 4; ++kk) {
            float4 v = hr[kk];
            acc0 += w[4 * kk + 0] * v.x; acc1 += w[4 * kk + 1] * v.y;
            acc2 += w[4 * kk + 2] * v.z; acc3 += w[4 * kk + 3] * v.w;
        }
        float hv = fmaxf(xpv + ((acc0 + acc1) + (acc2 + acc3)), 0.f);
        if (j < HH) { rowp[j] = hv; hbuf[cur ^ 1][j] = hv; }
        __syncthreads();
        cur ^= 1;
        rowp += HH;
    }
}

// ---------------------------------------------------------------------------
// Phase 3: o[r] = sum_j W_out[j] * h[r][j] + b_out. One wave per row,
// coalesced reads, butterfly shuffle reduction.
// ---------------------------------------------------------------------------
__global__ __launch_bounds__(256) void rnn_out(
    const float* __restrict__ hid, const float* __restrict__ Wout,
    const float* __restrict__ bout, float* __restrict__ out)
{
    const int wave = threadIdx.x >> 6;
    const int lane = threadIdx.x & 63;
    const long long r = (long long)blockIdx.x * 4 + wave;
    const float* hr = hid + r * HH;
    float p = 0.f;
#pragma unroll
    for (int m = 0; m < 4; ++m) {
        int idx = lane + 64 * m;
        if (idx < HH) p += Wout[idx] * hr[idx];
    }
#pragma unroll
    for (int off = 32; off; off >>= 1) p += __shfl_down(p, off, 64);
    if (lane == 0) out[r] = p + bout[0];
}

extern "C" void kernel_launch(void* const* d_in, const int* in_sizes, int n_in,
                              void* d_out, int out_size, void* d_ws, size_t ws_size,
                              hipStream_t stream)
{
    const float* x    = (const float*)d_in[0];  // [128,1024,100]
    const float* Wih  = (const float*)d_in[1];  // [200,100]
    const float* Whh  = (const float*)d_in[2];  // [200,200]
    const float* bih  = (const float*)d_in[3];  // [200]
    const float* bhh  = (const float*)d_in[4];  // [200]
    const float* Wout = (const float*)d_in[5];  // [1,200]
    const float* bout = (const float*)d_in[6];  // [1]

    float* out = (float*)d_out;                       // [128*1024] outputs first
    float* hid = out + (long long)BB * TT;            // [128*1024*200] hiddens

    rnn_xproj<<<(BB * TT) / 128, 256, 0, stream>>>(x, Wih, bih, bhh, hid);
    rnn_recur<<<BB, 256, 0, stream>>>(Whh, hid);
    rnn_out<<<(BB * TT) / 4, 256, 0, stream>>>(hid, Wout, bout, out);
}